// Round 6
// baseline (178.826 us; speedup 1.0000x reference)
//
#include <hip/hip_runtime.h>
#include <math.h>

#define D_MODEL 1024
#define N_HEADS 16
#define HEAD_DIM 64
#define BATCH 2
#define SEQ 2048
#define WIN_L 127
#define WIN_R 128

typedef float f32x4 __attribute__((ext_vector_type(4)));
typedef __bf16 bf16x8 __attribute__((ext_vector_type(8)));
typedef unsigned short ushort8_t __attribute__((ext_vector_type(8)));

typedef const __attribute__((address_space(1))) void* gptr_t;
typedef __attribute__((address_space(3))) void* lptr_t;

__device__ __forceinline__ unsigned short f2bf(float v) {
    unsigned u = __float_as_uint(v);
    unsigned r = (u + 0x7FFF + ((u >> 16) & 1)) >> 16;   // RNE
    return (unsigned short)r;
}

// ---------------------------------------------------------------------------
// fp32 -> bf16 for all three inputs in one launch.
// ---------------------------------------------------------------------------
#define NX_ELEM (4096 * 1024)
#define NW_ELEM (3072 * 1024)
#define NO_ELEM (1024 * 1024)

__global__ __launch_bounds__(256)
void cvt_all(const float* __restrict__ x, const float* __restrict__ wq,
             const float* __restrict__ wo, unsigned short* __restrict__ xb,
             unsigned short* __restrict__ wqb, unsigned short* __restrict__ wob)
{
    int i = (blockIdx.x * 256 + threadIdx.x) * 4;
    const float* src;
    unsigned short* dst;
    int off;
    if (i < NX_ELEM)                 { src = x;  dst = xb;  off = i; }
    else if (i < NX_ELEM + NW_ELEM)  { src = wq; dst = wqb; off = i - NX_ELEM; }
    else                             { src = wo; dst = wob; off = i - NX_ELEM - NW_ELEM; }
    float4 f = *(const float4*)(src + off);
    ushort4 o;
    o.x = f2bf(f.x); o.y = f2bf(f.y); o.z = f2bf(f.z); o.w = f2bf(f.w);
    *(ushort4*)(dst + off) = o;
}

// ---------------------------------------------------------------------------
// QKV GEMM (NT) with fused RoPE + layout epilogue.
// LDS union: staging (Al 128x32 | Bl 128x32 = 16 KB) and the per-wave
// transpose buffers (4 x 64x68 = 34.8 KB) share one 34.8 KB allocation —
// the transpose phase runs after the K-loop when Al/Bl are dead (one
// barrier guards the overwrite). 34.8 KB -> 4 blocks/CU; (256,4) caps
// VGPR at 128 for that occupancy.
// ---------------------------------------------------------------------------
__global__ __launch_bounds__(256, 4)
void gemm_qkv(const unsigned short* __restrict__ A,
              const unsigned short* __restrict__ B,
              unsigned short* __restrict__ qb,
              unsigned short* __restrict__ kb,
              unsigned short* __restrict__ vbT,
              int M, int N, int K)
{
    __shared__ __attribute__((aligned(16))) unsigned short U[17408]; // 34.8 KB
    unsigned short* Al = U;            // 128*32 = 4096
    unsigned short* Bl = U + 4096;     // 128*32 = 4096

    const int tid  = threadIdx.x;
    const int wave = tid >> 6;
    const int lane = tid & 63;
    const int m0 = blockIdx.y * 128;
    const int n0 = blockIdx.x * 128;

    const int wm = (wave >> 1) * 64;
    const int wn = (wave & 1) * 64;
    const int quad = lane >> 4;
    const int l16  = lane & 15;

    const int srow = lane >> 2;
    const int scol = (lane & 3) * 8;

    f32x4 acc[4][4] = {};

    for (int k0 = 0; k0 < K; k0 += 32) {
        __syncthreads();
#pragma unroll
        for (int l = 0; l < 2; ++l) {
            const int r = l * 64 + wave * 16 + srow;
            const unsigned short* gA = A + (size_t)(m0 + r) * K + k0 + scol;
            const unsigned short* gB = B + (size_t)(n0 + r) * K + k0 + scol;
            __builtin_amdgcn_global_load_lds((gptr_t)gA, (lptr_t)&Al[r * 32 + scol], 16, 0, 0);
            __builtin_amdgcn_global_load_lds((gptr_t)gB, (lptr_t)&Bl[r * 32 + scol], 16, 0, 0);
        }
        __syncthreads();

        bf16x8 af[4], bf[4];
#pragma unroll
        for (int i = 0; i < 4; ++i)
            af[i] = *(const bf16x8*)&Al[(wm + i * 16 + l16) * 32 + quad * 8];
#pragma unroll
        for (int j = 0; j < 4; ++j)
            bf[j] = *(const bf16x8*)&Bl[(wn + j * 16 + l16) * 32 + quad * 8];
#pragma unroll
        for (int i = 0; i < 4; ++i)
#pragma unroll
            for (int j = 0; j < 4; ++j)
                acc[i][j] = __builtin_amdgcn_mfma_f32_16x16x32_bf16(af[i], bf[j], acc[i][j], 0, 0, 0);
    }

    __syncthreads();   // all waves done reading Al/Bl before Tl overwrites them

    // ---- epilogue ----
    // C/D layout: col(d) = l16 + j*16, row(t) = quad*4 + r + i*16.
    const int which = (n0 >> 10);   // 0=q 1=k 2=v, uniform per block
    unsigned short* Tw = U + wave * 4352;   // 64*68 per wave

    if (which != 2) {
        // fused RoPE (fp32, in-register): d = jp*16+l16, partner acc[i][jp+2]
        float invf[2];
#pragma unroll
        for (int jp = 0; jp < 2; ++jp)
            invf[jp] = exp2f(-(float)(jp * 16 + l16) * 0.41524101186092f);
#pragma unroll
        for (int i = 0; i < 4; ++i) {
            const int tb = (m0 + wm + i * 16 + quad * 4) & 2047;
#pragma unroll
            for (int jp = 0; jp < 2; ++jp)
#pragma unroll
                for (int r = 0; r < 4; ++r) {
                    float s, c;
                    __sincosf((float)(tb + r) * invf[jp], &s, &c);
                    float x1 = acc[i][jp][r], x2 = acc[i][jp + 2][r];
                    acc[i][jp][r]     = x1 * c - x2 * s;
                    acc[i][jp + 2][r] = x2 * c + x1 * s;
                }
        }
        // Tw[t_loc][d], t_loc = i*16+quad*4+r, d = j*16+l16
#pragma unroll
        for (int i = 0; i < 4; ++i)
#pragma unroll
            for (int j = 0; j < 4; ++j)
#pragma unroll
                for (int r = 0; r < 4; ++r)
                    Tw[(i * 16 + quad * 4 + r) * 68 + j * 16 + l16] = f2bf(acc[i][j][r]);
    } else {
        // Tw[d][t_loc], d = j*16+l16, t_loc = i*16+quad*4+r (r contiguous)
#pragma unroll
        for (int i = 0; i < 4; ++i)
#pragma unroll
            for (int j = 0; j < 4; ++j) {
                ushort4 pv;
                pv.x = f2bf(acc[i][j][0]); pv.y = f2bf(acc[i][j][1]);
                pv.z = f2bf(acc[i][j][2]); pv.w = f2bf(acc[i][j][3]);
                *(ushort4*)&Tw[(j * 16 + l16) * 68 + i * 16 + quad * 4] = pv;
            }
    }

    // coalesced store phase (per-wave private buffer; lgkmcnt auto-waits)
    {
        const int h   = ((n0 + wn) >> 6) & 15;
        const int nb  = (m0 + wm) >> 11;
        const int tw0 = (m0 + wm) & 2047;
        const int lr8 = lane >> 3;          // 0..7
        const int lc8 = (lane & 7) * 8;     // element offset in row
        if (which != 2) {
            unsigned short* dst = (which == 0 ? qb : kb);
            unsigned short* gb = dst + (((size_t)nb * 16 + h) * SEQ + tw0) * 64;
#pragma unroll
            for (int c = 0; c < 8; ++c) {
                const int row = c * 8 + lr8;
                ushort4 lo = *(const ushort4*)&Tw[row * 68 + lc8];
                ushort4 hi = *(const ushort4*)&Tw[row * 68 + lc8 + 4];
                ushort8_t v8 = {lo.x, lo.y, lo.z, lo.w, hi.x, hi.y, hi.z, hi.w};
                *(ushort8_t*)&gb[row * 64 + lc8] = v8;   // lane-contiguous 1 KB
            }
        } else {
            unsigned short* gb = vbT + ((size_t)nb * 16 + h) * 64 * SEQ + tw0;
#pragma unroll
            for (int c = 0; c < 8; ++c) {
                const int drow = c * 8 + lr8;
                ushort4 lo = *(const ushort4*)&Tw[drow * 68 + lc8];
                ushort4 hi = *(const ushort4*)&Tw[drow * 68 + lc8 + 4];
                ushort8_t v8 = {lo.x, lo.y, lo.z, lo.w, hi.x, hi.y, hi.z, hi.w};
                *(ushort8_t*)&gb[(size_t)drow * SEQ + lc8] = v8;  // 128B rows
            }
        }
    }
}

// ---------------------------------------------------------------------------
// Out-projection GEMM (NT), fp32 out + bias. BM=64 (grid 512 = 2 blocks/CU;
// BM=128 gave 256 blocks = exactly 1/CU -> zero inter-block overlap).
// Wave tile 32x64: acc[2][4]. LDS 12.3 KB.
// ---------------------------------------------------------------------------
__global__ __launch_bounds__(256, 4)
void gemm_out(const unsigned short* __restrict__ A,
              const unsigned short* __restrict__ B,
              const float* __restrict__ bias, float* __restrict__ C,
              int M, int N, int K)
{
    __shared__ __attribute__((aligned(16))) unsigned short Al[64 * 32];
    __shared__ __attribute__((aligned(16))) unsigned short Bl[128 * 32];

    const int tid  = threadIdx.x;
    const int wave = tid >> 6;
    const int lane = tid & 63;
    const int m0 = blockIdx.y * 64;
    const int n0 = blockIdx.x * 128;

    const int wm = (wave >> 1) * 32;
    const int wn = (wave & 1) * 64;
    const int quad = lane >> 4;
    const int l16  = lane & 15;

    const int srow = lane >> 2;
    const int scol = (lane & 3) * 8;

    f32x4 acc[2][4] = {};

    for (int k0 = 0; k0 < K; k0 += 32) {
        __syncthreads();
        {
            const int r = wave * 16 + srow;        // 0..63
            const unsigned short* gA = A + (size_t)(m0 + r) * K + k0 + scol;
            __builtin_amdgcn_global_load_lds((gptr_t)gA, (lptr_t)&Al[r * 32 + scol], 16, 0, 0);
#pragma unroll
            for (int l = 0; l < 2; ++l) {
                const int rb = l * 64 + wave * 16 + srow;
                const unsigned short* gB = B + (size_t)(n0 + rb) * K + k0 + scol;
                __builtin_amdgcn_global_load_lds((gptr_t)gB, (lptr_t)&Bl[rb * 32 + scol], 16, 0, 0);
            }
        }
        __syncthreads();

        bf16x8 af[2], bf[4];
#pragma unroll
        for (int i = 0; i < 2; ++i)
            af[i] = *(const bf16x8*)&Al[(wm + i * 16 + l16) * 32 + quad * 8];
#pragma unroll
        for (int j = 0; j < 4; ++j)
            bf[j] = *(const bf16x8*)&Bl[(wn + j * 16 + l16) * 32 + quad * 8];
#pragma unroll
        for (int i = 0; i < 2; ++i)
#pragma unroll
            for (int j = 0; j < 4; ++j)
                acc[i][j] = __builtin_amdgcn_mfma_f32_16x16x32_bf16(af[i], bf[j], acc[i][j], 0, 0, 0);
    }

#pragma unroll
    for (int i = 0; i < 2; ++i) {
        const int row_base = m0 + wm + i * 16 + quad * 4;
#pragma unroll
        for (int j = 0; j < 4; ++j) {
            const int col = n0 + wn + j * 16 + l16;
            const float bv = bias[col];
#pragma unroll
            for (int r = 0; r < 4; ++r)
                C[(size_t)(row_base + r) * N + col] = acc[i][j][r] + bv;
        }
    }
}

// ---------------------------------------------------------------------------
// Banded MFMA flash attention.
// Block = (n, h, 64 queries), 4 waves x 16 queries, no inter-wave sharing.
// ---------------------------------------------------------------------------
__global__ __launch_bounds__(256, 4)
void attn_mfma(const unsigned short* __restrict__ qb,
               const unsigned short* __restrict__ kb,
               const unsigned short* __restrict__ vbT,
               unsigned short* __restrict__ attnb)
{
    __shared__ unsigned short Pl[4][16][296];   // per-wave 16 x 296 bf16

    const int tid  = threadIdx.x;
    const int w    = tid >> 6;
    const int lane = tid & 63;
    const int quad = lane >> 4;
    const int l16  = lane & 15;

    const int t0 = blockIdx.x * 64;
    const int h  = blockIdx.y;
    const int nB = blockIdx.z;
    const int nh = nB * 16 + h;

    const int tw  = t0 + w * 16;
    const int klo = max(0, tw - WIN_L) & ~31;          // 32-aligned band start
    const int khi = min(SEQ, tw + 16 + WIN_R);          // exclusive
    const int nchunk = (khi - klo + 31) >> 5;           // <= 9
    const int ntile  = nchunk * 2;                      // <= 18

    const unsigned short* qrow = qb + ((size_t)nh * SEQ + tw + l16) * 64;
    bf16x8 aq0 = *(const bf16x8*)(qrow + quad * 8);
    bf16x8 aq1 = *(const bf16x8*)(qrow + 32 + quad * 8);

    f32x4 sreg[18];
#pragma unroll
    for (int i = 0; i < 18; ++i) sreg[i] = (f32x4){0.f, 0.f, 0.f, 0.f};

    const unsigned short* kbase = kb + (size_t)nh * SEQ * 64;

    // ---- QK^T + mask ----
#pragma unroll
    for (int i = 0; i < 18; ++i) {
        if (i < ntile) {
            const int s0 = klo + i * 16;
            const int kr = min(s0 + l16, SEQ - 1);
            const unsigned short* krow = kbase + (size_t)kr * 64;
            bf16x8 bk0 = *(const bf16x8*)(krow + quad * 8);
            bf16x8 bk1 = *(const bf16x8*)(krow + 32 + quad * 8);
            f32x4 s = {0.f, 0.f, 0.f, 0.f};
            s = __builtin_amdgcn_mfma_f32_16x16x32_bf16(aq0, bk0, s, 0, 0, 0);
            s = __builtin_amdgcn_mfma_f32_16x16x32_bf16(aq1, bk1, s, 0, 0, 0);
            const int key = s0 + l16;
#pragma unroll
            for (int r = 0; r < 4; ++r) {
                const int t = tw + quad * 4 + r;
                const bool valid = (key < khi) && (key >= t - WIN_L) && (key <= t + WIN_R);
                sreg[i][r] = valid ? s[r] * 0.125f : -INFINITY;
            }
        }
    }

    // ---- softmax ----
    float mx[4] = {-INFINITY, -INFINITY, -INFINITY, -INFINITY};
#pragma unroll
    for (int i = 0; i < 18; ++i)
        if (i < ntile)
#pragma unroll
            for (int r = 0; r < 4; ++r) mx[r] = fmaxf(mx[r], sreg[i][r]);
#pragma unroll
    for (int r = 0; r < 4; ++r)
#pragma unroll
        for (int o = 8; o >= 1; o >>= 1) mx[r] = fmaxf(mx[r], __shfl_xor(mx[r], o, 64));

    float sm[4] = {0.f, 0.f, 0.f, 0.f};
#pragma unroll
    for (int i = 0; i < 18; ++i)
        if (i < ntile) {
#pragma unroll
            for (int r = 0; r < 4; ++r) {
                float p = __expf(sreg[i][r] - mx[r]);
                sm[r] += p;
                Pl[w][quad * 4 + r][i * 16 + l16] = f2bf(p);
            }
        }
#pragma unroll
    for (int r = 0; r < 4; ++r) {
#pragma unroll
        for (int o = 8; o >= 1; o >>= 1) sm[r] += __shfl_xor(sm[r], o, 64);
        sm[r] = 1.0f / sm[r];
    }

    // ---- PV ----
    f32x4 oacc[4] = {};
    const unsigned short* vbase = vbT + (size_t)nh * 64 * SEQ;
#pragma unroll
    for (int kc = 0; kc < 9; ++kc) {
        if (kc < nchunk) {
            bf16x8 pf = *(const bf16x8*)&Pl[w][l16][kc * 32 + quad * 8];
            const int toff = klo + kc * 32 + quad * 8;
#pragma unroll
            for (int j = 0; j < 4; ++j) {
                bf16x8 vf = *(const bf16x8*)(vbase + (size_t)(j * 16 + l16) * SEQ + toff);
                oacc[j] = __builtin_amdgcn_mfma_f32_16x16x32_bf16(pf, vf, oacc[j], 0, 0, 0);
            }
        }
    }

    // ---- normalize + store ----
#pragma unroll
    for (int j = 0; j < 4; ++j)
#pragma unroll
        for (int r = 0; r < 4; ++r) {
            const int t = tw + quad * 4 + r;
            attnb[((size_t)(nB * SEQ + t)) * D_MODEL + h * 64 + j * 16 + l16] =
                f2bf(oacc[j][r] * sm[r]);
        }
}

// ---------------------------------------------------------------------------
extern "C" void kernel_launch(void* const* d_in, const int* in_sizes, int n_in,
                              void* d_out, int out_size, void* d_ws, size_t ws_size,
                              hipStream_t stream)
{
    (void)in_sizes; (void)n_in; (void)out_size; (void)ws_size;
    const float* x     = (const float*)d_in[0];
    const float* w_qkv = (const float*)d_in[1];
    const float* w_out = (const float*)d_in[2];
    const float* b_out = (const float*)d_in[3];
    float* out = (float*)d_out;

    const int M = BATCH * SEQ;                 // 4096

    // ws layout (ushorts), 41.9 MB total:
    //   qb | kb | vbT | wob | xb | wqb   (attnb reuses xb after QKV GEMM)
    unsigned short* qb  = (unsigned short*)d_ws;
    unsigned short* kb  = qb  + (size_t)4194304;
    unsigned short* vbT = kb  + (size_t)4194304;
    unsigned short* wob = vbT + (size_t)4194304;
    unsigned short* xb  = wob + (size_t)1048576;
    unsigned short* wqb = xb  + (size_t)4194304;
    unsigned short* attnb = xb;

    dim3 blk(256);

    // 0) fp32 -> bf16 conversions (single launch)
    cvt_all<<<dim3((NX_ELEM + NW_ELEM + NO_ELEM) / 4 / 256), blk, 0, stream>>>(
        x, w_qkv, w_out, xb, wqb, wob);

    // 1) fused QKV projection + RoPE -> qb,kb [n,h,t,64], vbT [n,h,64,t] (bf16)
    gemm_qkv<<<dim3(3 * D_MODEL / 128, M / 128), blk, 0, stream>>>(
        xb, wqb, qb, kb, vbT, M, 3 * D_MODEL, D_MODEL);

    // 2) banded MFMA attention -> attnb [n,t,D] bf16
    attn_mfma<<<dim3(SEQ / 64, N_HEADS, BATCH), blk, 0, stream>>>(qb, kb, vbT, attnb);

    // 3) out = attn @ w_out^T + b_out   (BM=64: grid 8 x 64 = 512 blocks)
    gemm_out<<<dim3(D_MODEL / 128, M / 64), blk, 0, stream>>>(
        attnb, wob, b_out, out, M, D_MODEL, D_MODEL);
}

// Round 7
// 171.078 us; speedup vs baseline: 1.0453x; 1.0453x over previous
//
#include <hip/hip_runtime.h>
#include <math.h>

#define D_MODEL 1024
#define N_HEADS 16
#define HEAD_DIM 64
#define BATCH 2
#define SEQ 2048
#define WIN_L 127
#define WIN_R 128

typedef float f32x4 __attribute__((ext_vector_type(4)));
typedef __bf16 bf16x8 __attribute__((ext_vector_type(8)));
typedef unsigned short ushort8_t __attribute__((ext_vector_type(8)));

typedef const __attribute__((address_space(1))) void* gptr_t;
typedef __attribute__((address_space(3))) void* lptr_t;

__device__ __forceinline__ unsigned short f2bf(float v) {
    unsigned u = __float_as_uint(v);
    unsigned r = (u + 0x7FFF + ((u >> 16) & 1)) >> 16;   // RNE
    return (unsigned short)r;
}

// ---------------------------------------------------------------------------
// fp32 -> bf16 for all three inputs in one launch.
// ---------------------------------------------------------------------------
#define NX_ELEM (4096 * 1024)
#define NW_ELEM (3072 * 1024)
#define NO_ELEM (1024 * 1024)

__global__ __launch_bounds__(256)
void cvt_all(const float* __restrict__ x, const float* __restrict__ wq,
             const float* __restrict__ wo, unsigned short* __restrict__ xb,
             unsigned short* __restrict__ wqb, unsigned short* __restrict__ wob)
{
    int i = (blockIdx.x * 256 + threadIdx.x) * 4;
    const float* src;
    unsigned short* dst;
    int off;
    if (i < NX_ELEM)                 { src = x;  dst = xb;  off = i; }
    else if (i < NX_ELEM + NW_ELEM)  { src = wq; dst = wqb; off = i - NX_ELEM; }
    else                             { src = wo; dst = wob; off = i - NX_ELEM - NW_ELEM; }
    float4 f = *(const float4*)(src + off);
    ushort4 o;
    o.x = f2bf(f.x); o.y = f2bf(f.y); o.z = f2bf(f.z); o.w = f2bf(f.w);
    *(ushort4*)(dst + off) = o;
}

// ---------------------------------------------------------------------------
// QKV GEMM (NT) with fused RoPE + layout epilogue.
// K-loop: BK=64 per barrier, staged as TWO BK=32 panels (keeps the
// row-stride-64B bank layout and the lane-linear global_load_lds constraint;
// a single 128B-stride panel would be a 16-way bank conflict on frag reads).
// Halves the vmcnt(0) barrier drains: 16 iters x 32 MFMA, 8 loads in flight.
// LDS: staging 32 KB unioned with per-wave transpose buffers (34.8 KB).
// (256,2): acc stays in arch VGPRs (R6's (256,4) forced AGPR moves).
// ---------------------------------------------------------------------------
__global__ __launch_bounds__(256, 2)
void gemm_qkv(const unsigned short* __restrict__ A,
              const unsigned short* __restrict__ B,
              unsigned short* __restrict__ qb,
              unsigned short* __restrict__ kb,
              unsigned short* __restrict__ vbT,
              int M, int N, int K)
{
    __shared__ __attribute__((aligned(16))) unsigned short U[17408]; // 34.8 KB
    unsigned short* Al0 = U;             // 128*32
    unsigned short* Bl0 = U + 4096;
    unsigned short* Al1 = U + 8192;
    unsigned short* Bl1 = U + 12288;

    const int tid  = threadIdx.x;
    const int wave = tid >> 6;
    const int lane = tid & 63;
    const int m0 = blockIdx.y * 128;
    const int n0 = blockIdx.x * 128;

    const int wm = (wave >> 1) * 64;
    const int wn = (wave & 1) * 64;
    const int quad = lane >> 4;
    const int l16  = lane & 15;

    const int srow = lane >> 2;          // 0..15
    const int scol = (lane & 3) * 8;     // 0,8,16,24

    f32x4 acc[4][4] = {};

    for (int k0 = 0; k0 < K; k0 += 64) {
        __syncthreads();
#pragma unroll
        for (int l = 0; l < 2; ++l) {
            const int r = l * 64 + wave * 16 + srow;
            const unsigned short* gA = A + (size_t)(m0 + r) * K + k0 + scol;
            const unsigned short* gB = B + (size_t)(n0 + r) * K + k0 + scol;
            __builtin_amdgcn_global_load_lds((gptr_t)gA,        (lptr_t)&Al0[r * 32 + scol], 16, 0, 0);
            __builtin_amdgcn_global_load_lds((gptr_t)gB,        (lptr_t)&Bl0[r * 32 + scol], 16, 0, 0);
            __builtin_amdgcn_global_load_lds((gptr_t)(gA + 32), (lptr_t)&Al1[r * 32 + scol], 16, 0, 0);
            __builtin_amdgcn_global_load_lds((gptr_t)(gB + 32), (lptr_t)&Bl1[r * 32 + scol], 16, 0, 0);
        }
        __syncthreads();

#pragma unroll
        for (int kh = 0; kh < 2; ++kh) {
            const unsigned short* Ap = kh ? Al1 : Al0;
            const unsigned short* Bp = kh ? Bl1 : Bl0;
            bf16x8 af[4], bf[4];
#pragma unroll
            for (int i = 0; i < 4; ++i)
                af[i] = *(const bf16x8*)&Ap[(wm + i * 16 + l16) * 32 + quad * 8];
#pragma unroll
            for (int j = 0; j < 4; ++j)
                bf[j] = *(const bf16x8*)&Bp[(wn + j * 16 + l16) * 32 + quad * 8];
#pragma unroll
            for (int i = 0; i < 4; ++i)
#pragma unroll
                for (int j = 0; j < 4; ++j)
                    acc[i][j] = __builtin_amdgcn_mfma_f32_16x16x32_bf16(af[i], bf[j], acc[i][j], 0, 0, 0);
        }
    }

    __syncthreads();   // all waves done reading staging before Tl overwrites

    // ---- epilogue ----
    // C/D layout: col(d) = l16 + j*16, row(t) = quad*4 + r + i*16.
    const int which = (n0 >> 10);   // 0=q 1=k 2=v, uniform per block
    unsigned short* Tw = U + wave * 4352;   // 64*68 per wave

    if (which != 2) {
        // fused RoPE (fp32, in-register): d = jp*16+l16, partner acc[i][jp+2]
        float invf[2];
#pragma unroll
        for (int jp = 0; jp < 2; ++jp)
            invf[jp] = exp2f(-(float)(jp * 16 + l16) * 0.41524101186092f);
#pragma unroll
        for (int i = 0; i < 4; ++i) {
            const int tb = (m0 + wm + i * 16 + quad * 4) & 2047;
#pragma unroll
            for (int jp = 0; jp < 2; ++jp)
#pragma unroll
                for (int r = 0; r < 4; ++r) {
                    float s, c;
                    __sincosf((float)(tb + r) * invf[jp], &s, &c);
                    float x1 = acc[i][jp][r], x2 = acc[i][jp + 2][r];
                    acc[i][jp][r]     = x1 * c - x2 * s;
                    acc[i][jp + 2][r] = x2 * c + x1 * s;
                }
        }
        // Tw[t_loc][d], t_loc = i*16+quad*4+r, d = j*16+l16
#pragma unroll
        for (int i = 0; i < 4; ++i)
#pragma unroll
            for (int j = 0; j < 4; ++j)
#pragma unroll
                for (int r = 0; r < 4; ++r)
                    Tw[(i * 16 + quad * 4 + r) * 68 + j * 16 + l16] = f2bf(acc[i][j][r]);
    } else {
        // Tw[d][t_loc], d = j*16+l16, t_loc = i*16+quad*4+r (r contiguous)
#pragma unroll
        for (int i = 0; i < 4; ++i)
#pragma unroll
            for (int j = 0; j < 4; ++j) {
                ushort4 pv;
                pv.x = f2bf(acc[i][j][0]); pv.y = f2bf(acc[i][j][1]);
                pv.z = f2bf(acc[i][j][2]); pv.w = f2bf(acc[i][j][3]);
                *(ushort4*)&Tw[(j * 16 + l16) * 68 + i * 16 + quad * 4] = pv;
            }
    }

    // coalesced store phase (per-wave private buffer; lgkmcnt auto-waits)
    {
        const int h   = ((n0 + wn) >> 6) & 15;
        const int nb  = (m0 + wm) >> 11;
        const int tw0 = (m0 + wm) & 2047;
        const int lr8 = lane >> 3;          // 0..7
        const int lc8 = (lane & 7) * 8;     // element offset in row
        if (which != 2) {
            unsigned short* dst = (which == 0 ? qb : kb);
            unsigned short* gb = dst + (((size_t)nb * 16 + h) * SEQ + tw0) * 64;
#pragma unroll
            for (int c = 0; c < 8; ++c) {
                const int row = c * 8 + lr8;
                ushort4 lo = *(const ushort4*)&Tw[row * 68 + lc8];
                ushort4 hi = *(const ushort4*)&Tw[row * 68 + lc8 + 4];
                ushort8_t v8 = {lo.x, lo.y, lo.z, lo.w, hi.x, hi.y, hi.z, hi.w};
                *(ushort8_t*)&gb[row * 64 + lc8] = v8;   // lane-contiguous 1 KB
            }
        } else {
            unsigned short* gb = vbT + ((size_t)nb * 16 + h) * 64 * SEQ + tw0;
#pragma unroll
            for (int c = 0; c < 8; ++c) {
                const int drow = c * 8 + lr8;
                ushort4 lo = *(const ushort4*)&Tw[drow * 68 + lc8];
                ushort4 hi = *(const ushort4*)&Tw[drow * 68 + lc8 + 4];
                ushort8_t v8 = {lo.x, lo.y, lo.z, lo.w, hi.x, hi.y, hi.z, hi.w};
                *(ushort8_t*)&gb[(size_t)drow * SEQ + lc8] = v8;  // 128B rows
            }
        }
    }
}

// ---------------------------------------------------------------------------
// Out-projection GEMM (NT), fp32 out + bias. BM=64 (grid 512 = 2 blocks/CU).
// BK=64 via two BK=32 panels; 16 barrier drains. LDS 24 KB.
// ---------------------------------------------------------------------------
__global__ __launch_bounds__(256, 4)
void gemm_out(const unsigned short* __restrict__ A,
              const unsigned short* __restrict__ B,
              const float* __restrict__ bias, float* __restrict__ C,
              int M, int N, int K)
{
    __shared__ __attribute__((aligned(16))) unsigned short Al0[64 * 32];
    __shared__ __attribute__((aligned(16))) unsigned short Al1[64 * 32];
    __shared__ __attribute__((aligned(16))) unsigned short Bl0[128 * 32];
    __shared__ __attribute__((aligned(16))) unsigned short Bl1[128 * 32];

    const int tid  = threadIdx.x;
    const int wave = tid >> 6;
    const int lane = tid & 63;
    const int m0 = blockIdx.y * 64;
    const int n0 = blockIdx.x * 128;

    const int wm = (wave >> 1) * 32;
    const int wn = (wave & 1) * 64;
    const int quad = lane >> 4;
    const int l16  = lane & 15;

    const int srow = lane >> 2;
    const int scol = (lane & 3) * 8;

    f32x4 acc[2][4] = {};

    for (int k0 = 0; k0 < K; k0 += 64) {
        __syncthreads();
        {
            const int r = wave * 16 + srow;        // 0..63
            const unsigned short* gA = A + (size_t)(m0 + r) * K + k0 + scol;
            __builtin_amdgcn_global_load_lds((gptr_t)gA,        (lptr_t)&Al0[r * 32 + scol], 16, 0, 0);
            __builtin_amdgcn_global_load_lds((gptr_t)(gA + 32), (lptr_t)&Al1[r * 32 + scol], 16, 0, 0);
#pragma unroll
            for (int l = 0; l < 2; ++l) {
                const int rb = l * 64 + wave * 16 + srow;
                const unsigned short* gB = B + (size_t)(n0 + rb) * K + k0 + scol;
                __builtin_amdgcn_global_load_lds((gptr_t)gB,        (lptr_t)&Bl0[rb * 32 + scol], 16, 0, 0);
                __builtin_amdgcn_global_load_lds((gptr_t)(gB + 32), (lptr_t)&Bl1[rb * 32 + scol], 16, 0, 0);
            }
        }
        __syncthreads();

#pragma unroll
        for (int kh = 0; kh < 2; ++kh) {
            const unsigned short* Ap = kh ? Al1 : Al0;
            const unsigned short* Bp = kh ? Bl1 : Bl0;
            bf16x8 af[2], bf[4];
#pragma unroll
            for (int i = 0; i < 2; ++i)
                af[i] = *(const bf16x8*)&Ap[(wm + i * 16 + l16) * 32 + quad * 8];
#pragma unroll
            for (int j = 0; j < 4; ++j)
                bf[j] = *(const bf16x8*)&Bp[(wn + j * 16 + l16) * 32 + quad * 8];
#pragma unroll
            for (int i = 0; i < 2; ++i)
#pragma unroll
                for (int j = 0; j < 4; ++j)
                    acc[i][j] = __builtin_amdgcn_mfma_f32_16x16x32_bf16(af[i], bf[j], acc[i][j], 0, 0, 0);
        }
    }

#pragma unroll
    for (int i = 0; i < 2; ++i) {
        const int row_base = m0 + wm + i * 16 + quad * 4;
#pragma unroll
        for (int j = 0; j < 4; ++j) {
            const int col = n0 + wn + j * 16 + l16;
            const float bv = bias[col];
#pragma unroll
            for (int r = 0; r < 4; ++r)
                C[(size_t)(row_base + r) * N + col] = acc[i][j][r] + bv;
        }
    }
}

// ---------------------------------------------------------------------------
// Banded MFMA flash attention.
// Block = (n, h, 64 queries), 4 waves x 16 queries, no inter-wave sharing.
// ---------------------------------------------------------------------------
__global__ __launch_bounds__(256, 4)
void attn_mfma(const unsigned short* __restrict__ qb,
               const unsigned short* __restrict__ kb,
               const unsigned short* __restrict__ vbT,
               unsigned short* __restrict__ attnb)
{
    __shared__ unsigned short Pl[4][16][296];   // per-wave 16 x 296 bf16

    const int tid  = threadIdx.x;
    const int w    = tid >> 6;
    const int lane = tid & 63;
    const int quad = lane >> 4;
    const int l16  = lane & 15;

    const int t0 = blockIdx.x * 64;
    const int h  = blockIdx.y;
    const int nB = blockIdx.z;
    const int nh = nB * 16 + h;

    const int tw  = t0 + w * 16;
    const int klo = max(0, tw - WIN_L) & ~31;          // 32-aligned band start
    const int khi = min(SEQ, tw + 16 + WIN_R);          // exclusive
    const int nchunk = (khi - klo + 31) >> 5;           // <= 9
    const int ntile  = nchunk * 2;                      // <= 18

    const unsigned short* qrow = qb + ((size_t)nh * SEQ + tw + l16) * 64;
    bf16x8 aq0 = *(const bf16x8*)(qrow + quad * 8);
    bf16x8 aq1 = *(const bf16x8*)(qrow + 32 + quad * 8);

    f32x4 sreg[18];
#pragma unroll
    for (int i = 0; i < 18; ++i) sreg[i] = (f32x4){0.f, 0.f, 0.f, 0.f};

    const unsigned short* kbase = kb + (size_t)nh * SEQ * 64;

    // ---- QK^T + mask ----
#pragma unroll
    for (int i = 0; i < 18; ++i) {
        if (i < ntile) {
            const int s0 = klo + i * 16;
            const int kr = min(s0 + l16, SEQ - 1);
            const unsigned short* krow = kbase + (size_t)kr * 64;
            bf16x8 bk0 = *(const bf16x8*)(krow + quad * 8);
            bf16x8 bk1 = *(const bf16x8*)(krow + 32 + quad * 8);
            f32x4 s = {0.f, 0.f, 0.f, 0.f};
            s = __builtin_amdgcn_mfma_f32_16x16x32_bf16(aq0, bk0, s, 0, 0, 0);
            s = __builtin_amdgcn_mfma_f32_16x16x32_bf16(aq1, bk1, s, 0, 0, 0);
            const int key = s0 + l16;
#pragma unroll
            for (int r = 0; r < 4; ++r) {
                const int t = tw + quad * 4 + r;
                const bool valid = (key < khi) && (key >= t - WIN_L) && (key <= t + WIN_R);
                sreg[i][r] = valid ? s[r] * 0.125f : -INFINITY;
            }
        }
    }

    // ---- softmax ----
    float mx[4] = {-INFINITY, -INFINITY, -INFINITY, -INFINITY};
#pragma unroll
    for (int i = 0; i < 18; ++i)
        if (i < ntile)
#pragma unroll
            for (int r = 0; r < 4; ++r) mx[r] = fmaxf(mx[r], sreg[i][r]);
#pragma unroll
    for (int r = 0; r < 4; ++r)
#pragma unroll
        for (int o = 8; o >= 1; o >>= 1) mx[r] = fmaxf(mx[r], __shfl_xor(mx[r], o, 64));

    float sm[4] = {0.f, 0.f, 0.f, 0.f};
#pragma unroll
    for (int i = 0; i < 18; ++i)
        if (i < ntile) {
#pragma unroll
            for (int r = 0; r < 4; ++r) {
                float p = __expf(sreg[i][r] - mx[r]);
                sm[r] += p;
                Pl[w][quad * 4 + r][i * 16 + l16] = f2bf(p);
            }
        }
#pragma unroll
    for (int r = 0; r < 4; ++r) {
#pragma unroll
        for (int o = 8; o >= 1; o >>= 1) sm[r] += __shfl_xor(sm[r], o, 64);
        sm[r] = 1.0f / sm[r];
    }

    // ---- PV ----
    f32x4 oacc[4] = {};
    const unsigned short* vbase = vbT + (size_t)nh * 64 * SEQ;
#pragma unroll
    for (int kc = 0; kc < 9; ++kc) {
        if (kc < nchunk) {
            bf16x8 pf = *(const bf16x8*)&Pl[w][l16][kc * 32 + quad * 8];
            const int toff = klo + kc * 32 + quad * 8;
#pragma unroll
            for (int j = 0; j < 4; ++j) {
                bf16x8 vf = *(const bf16x8*)(vbase + (size_t)(j * 16 + l16) * SEQ + toff);
                oacc[j] = __builtin_amdgcn_mfma_f32_16x16x32_bf16(pf, vf, oacc[j], 0, 0, 0);
            }
        }
    }

    // ---- normalize + store ----
#pragma unroll
    for (int j = 0; j < 4; ++j)
#pragma unroll
        for (int r = 0; r < 4; ++r) {
            const int t = tw + quad * 4 + r;
            attnb[((size_t)(nB * SEQ + t)) * D_MODEL + h * 64 + j * 16 + l16] =
                f2bf(oacc[j][r] * sm[r]);
        }
}

// ---------------------------------------------------------------------------
extern "C" void kernel_launch(void* const* d_in, const int* in_sizes, int n_in,
                              void* d_out, int out_size, void* d_ws, size_t ws_size,
                              hipStream_t stream)
{
    (void)in_sizes; (void)n_in; (void)out_size; (void)ws_size;
    const float* x     = (const float*)d_in[0];
    const float* w_qkv = (const float*)d_in[1];
    const float* w_out = (const float*)d_in[2];
    const float* b_out = (const float*)d_in[3];
    float* out = (float*)d_out;

    const int M = BATCH * SEQ;                 // 4096

    // ws layout (ushorts), 41.9 MB total:
    //   qb | kb | vbT | wob | xb | wqb   (attnb reuses xb after QKV GEMM)
    unsigned short* qb  = (unsigned short*)d_ws;
    unsigned short* kb  = qb  + (size_t)4194304;
    unsigned short* vbT = kb  + (size_t)4194304;
    unsigned short* wob = vbT + (size_t)4194304;
    unsigned short* xb  = wob + (size_t)1048576;
    unsigned short* wqb = xb  + (size_t)4194304;
    unsigned short* attnb = xb;

    dim3 blk(256);

    // 0) fp32 -> bf16 conversions (single launch)
    cvt_all<<<dim3((NX_ELEM + NW_ELEM + NO_ELEM) / 4 / 256), blk, 0, stream>>>(
        x, w_qkv, w_out, xb, wqb, wob);

    // 1) fused QKV projection + RoPE -> qb,kb [n,h,t,64], vbT [n,h,64,t] (bf16)
    gemm_qkv<<<dim3(3 * D_MODEL / 128, M / 128), blk, 0, stream>>>(
        xb, wqb, qb, kb, vbT, M, 3 * D_MODEL, D_MODEL);

    // 2) banded MFMA attention -> attnb [n,t,D] bf16
    attn_mfma<<<dim3(SEQ / 64, N_HEADS, BATCH), blk, 0, stream>>>(qb, kb, vbT, attnb);

    // 3) out = attn @ w_out^T + b_out   (BM=64: grid 8 x 64 = 512 blocks)
    gemm_out<<<dim3(D_MODEL / 128, M / 64), blk, 0, stream>>>(
        attnb, wob, b_out, out, M, D_MODEL, D_MODEL);
}